// Round 5
// baseline (200.979 us; speedup 1.0000x reference)
//
#include <hip/hip_runtime.h>

// Signature-kernel MMD via Goursat PDE — round 5.
// R4 postmortem: __builtin_elementwise_fma(f2) did NOT lower to v_pk_fma_f32
// (instr/row ~90 vs R2's ~71); harness overhead is fixed ~40-47us, so only
// the pde kernel matters. R5: (1) inline-asm v_pk_fma_f32 for the dots
// (32 scalar fma -> 16 pk), (2) dX rows loaded with per-lane vector
// global_load_dwordx4 (same addr across lanes = broadcast; opaque-zero
// mbcnt(0,0) defeats scalarization) straight into VGPR pairs — zero v_movs,
// (3) otherwise R2's proven structure: diff precompute, 2112x4-wave grid
// (1 pair/wave = occupancy optimum), DPP scan, fused atomicAdd reduce.

typedef float f2 __attribute__((ext_vector_type(2)));

#define XY_BLOCKS 1024
#define TRI_BLOCKS 544
#define NBLOCKS (XY_BLOCKS + 2 * TRI_BLOCKS)   // 2112 blocks x 4 waves
#define DINC_PER 130048                         // 64*127*16 floats

template <int C, int RM, int BM, bool BC>
__device__ __forceinline__ float dpp0(float x) {
    return __builtin_bit_cast(float, __builtin_amdgcn_update_dpp(
        0, __builtin_bit_cast(int, x), C, RM, BM, BC));
}

// 64-lane inclusive prefix sum, pure VALU (6 dependent adds).
__device__ __forceinline__ float wave_scan_incl(float v) {
    v += dpp0<0x111, 0xf, 0xf, true>(v);   // row_shr:1
    v += dpp0<0x112, 0xf, 0xf, true>(v);   // row_shr:2
    v += dpp0<0x114, 0xf, 0xf, true>(v);   // row_shr:4
    v += dpp0<0x118, 0xf, 0xf, true>(v);   // row_shr:8
    v += dpp0<0x142, 0xa, 0xf, false>(v);  // row_bcast:15 -> rows 1,3
    v += dpp0<0x143, 0xc, 0xf, false>(v);  // row_bcast:31 -> rows 2,3
    return v;
}

// lane l gets lane l-1's x; lane 0 gets `oldv`.
__device__ __forceinline__ float wave_shr1(float x, float oldv) {
    return __builtin_bit_cast(float, __builtin_amdgcn_update_dpp(
        __builtin_bit_cast(int, oldv), __builtin_bit_cast(int, x),
        0x138, 0xf, 0xf, false));          // wave_shr:1
}

// packed dual-fp32 FMA (VOP3P) — forced via asm so it actually emits.
__device__ __forceinline__ f2 pk_fma(f2 a, f2 b, f2 c) {
    f2 d;
    asm("v_pk_fma_f32 %0, %1, %2, %3" : "=v"(d) : "v"(a), "v"(b), "v"(c));
    return d;
}

// dX row r as 8 f2, via per-lane vector loads (broadcast; Ar4 is divergent-
// looking so these stay global_load_dwordx4 into VGPRs, no SGPR round-trip).
__device__ __forceinline__ void load_xrow(f2* x, const float4* Ar4, int r) {
#pragma unroll
    for (int q = 0; q < 4; ++q) {
        float4 v = Ar4[4 * r + q];
        x[2*q]   = f2{v.x, v.y};
        x[2*q+1] = f2{v.z, v.w};
    }
}

// one PDE row; xr = dX row r (VGPR pairs), ya/yb = per-lane dY cols 2l, 2l+1
__device__ __forceinline__ void pde_row(
    const f2* xr, const f2* ya, const f2* yb,
    float& g_lo, float& g_hi, int lane)
{
    f2 a0 = f2{-0.25f, -0.25f}, a1 = f2{-0.25f, -0.25f};
    f2 b0 = f2{-0.25f, -0.25f}, b1 = f2{-0.25f, -0.25f};
#pragma unroll
    for (int d = 0; d < 8; d += 2) {
        a0 = pk_fma(xr[d],   ya[d],   a0);
        a1 = pk_fma(xr[d+1], ya[d+1], a1);
        b0 = pk_fma(xr[d],   yb[d],   b0);
        b1 = pk_fma(xr[d+1], yb[d+1], b1);
    }
    const f2 sA = a0 + a1, sB = b0 + b1;
    const float i0 = sA.x + sA.y;                  // inc(r,2l)   - 1
    const float i1 = sB.x + sB.y;                  // inc(r,2l+1) - 1
    const float gl = wave_shr1(g_hi, 1.0f);        // G[r][2l], lane0 -> 1
    const float c0 = fmaf(gl, i0, g_lo);
    const float c1 = (lane == 63) ? 0.0f : fmaf(g_lo, i1, g_hi);
    const float S = wave_scan_incl(c0 + c1);
    g_lo = (S - c1) + 1.0f;
    g_hi = S + 1.0f;
}

// ---- kernel 1: path increments X,Y -> ws ----
__global__ __launch_bounds__(256) void sig_diff(
    const float* __restrict__ X, const float* __restrict__ Y,
    float* __restrict__ dInc)
{
    int i = blockIdx.x * 256 + threadIdx.x;   // float4 id, 65024 total
    if (i >= 65024) return;
    int which = (i >= 32512) ? 1 : 0;
    int j = i - which * 32512;
    int a = j / 508;                          // 127*4 float4 per path
    int rq = j - a * 508;
    const float* S = which ? Y : X;
    const float4* p = (const float4*)(S + a * 2048) + rq;
    float4 v0 = p[0], v1 = p[4];
    float4 d;
    d.x = v1.x - v0.x; d.y = v1.y - v0.y;
    d.z = v1.z - v0.z; d.w = v1.w - v0.w;
    ((float4*)dInc)[i] = d;
}

// ---- kernel 2: PDE, 1 pair/wave, fused block reduction ----
__global__ __launch_bounds__(256) void sig_pde5(
    const float* __restrict__ dInc, float* __restrict__ outp)
{
    __shared__ float red[4];
    const int wv = threadIdx.x >> 6, lane = threadIdx.x & 63;
    const int B = blockIdx.x;

    int g, a, b;
    if (B < XY_BLOCKS) {                       // XY gram: dense 64x64
        g = 2; a = B >> 4; b = ((B & 15) << 2) + wv;
    } else {                                   // XX / YY: upper triangle
        int t = B - XY_BLOCKS; g = 0;
        if (t >= TRI_BLOCKS) { t -= TRI_BLOCKS; g = 1; }
        int aa = 0;
        for (;;) { int nb = (67 - aa) >> 2; if (t < nb) break; t -= nb; ++aa; }
        a = aa; b = aa + (t << 2) + wv;
    }
    float weight = (g == 2) ? (-2.0f / 4096.0f)
                            : ((a == b ? 1.0f : 2.0f) / 4096.0f);
    if (g < 2 && b > 63) { b = 63; weight = 0.0f; }   // pad waves: masked

    const float* dA = (g == 1) ? (dInc + DINC_PER) : dInc;   // row paths
    const float* dB = (g == 0) ? dInc : (dInc + DINC_PER);   // col paths

    // per-lane dY cols j=2l, 2l+1
    f2 ya[8], yb[8];
    {
        const int j0 = lane << 1;
        const int j1 = (j0 + 1 < 127) ? j0 + 1 : 126;  // lane63 clamp (masked)
        const float4* A4 = (const float4*)(dB + b * 2032 + j0 * 16);
        const float4* B4 = (const float4*)(dB + b * 2032 + j1 * 16);
#pragma unroll
        for (int q = 0; q < 4; ++q) {
            float4 va = A4[q], vb = B4[q];
            ya[2*q]   = f2{va.x, va.y};  ya[2*q+1] = f2{va.z, va.w};
            yb[2*q]   = f2{vb.x, vb.y};  yb[2*q+1] = f2{vb.z, vb.w};
        }
    }

    // dX base; opaque zero keeps the address formally divergent so row loads
    // stay VMEM vector loads (broadcast) instead of s_load + v_mov.
    const int dz = __builtin_amdgcn_mbcnt_lo(0u, 0u);   // == 0, opaque
    const float4* Ar4 = (const float4*)(dA + a * 2032) + dz;

    f2 xa[8], xb[8];
    load_xrow(xa, Ar4, 0);

    float g_lo = 1.0f, g_hi = 1.0f;
    for (int r = 0; r < 126; r += 2) {
        load_xrow(xb, Ar4, r + 1);             // prefetch next row
        pde_row(xa, ya, yb, g_lo, g_hi, lane);
        load_xrow(xa, Ar4, r + 2);             // prefetch row after
        pde_row(xb, ya, yb, g_lo, g_hi, lane);
    }
    pde_row(xa, ya, yb, g_lo, g_hi, lane);     // row 126

    const float kab = __builtin_bit_cast(float,
        __builtin_amdgcn_readlane(__builtin_bit_cast(int, g_lo), 63));
    if (lane == 0) red[wv] = weight * kab;
    __syncthreads();
    if (threadIdx.x == 0)
        atomicAdd(outp, (red[0] + red[1]) + (red[2] + red[3]));
}

// ---- fallback (ws too small): R4's self-contained single kernel ----
__device__ __forceinline__ void pde_row_q(
    const f2* xr, const f2* ya, const f2* yb,
    float& qpA, float& qpB, float& g_lo, float& g_hi, int lane)
{
    f2 s0 = 0.0f, s1 = 0.0f, t0 = 0.0f, t1 = 0.0f;
#pragma unroll
    for (int d = 0; d < 8; d += 2) {
        s0 = pk_fma(xr[d], ya[d], s0);   s1 = pk_fma(xr[d+1], ya[d+1], s1);
        t0 = pk_fma(xr[d], yb[d], t0);   t1 = pk_fma(xr[d+1], yb[d+1], t1);
    }
    const f2 sA = s0 + s1, sB = t0 + t1;
    const float hA = sA.x + sA.y, hB = sB.x + sB.y;
    const float i0 = hA - qpA;  qpA = hA + 1.0f;
    const float i1 = hB - qpB;  qpB = hB + 1.0f;
    const float gl = wave_shr1(g_hi, 1.0f);
    const float c0 = fmaf(gl, i0, g_lo);
    const float c1 = (lane == 63) ? 0.0f : fmaf(g_lo, i1, g_hi);
    const float S = wave_scan_incl(c0 + c1);
    g_lo = (S - c1) + 1.0f;
    g_hi = S + 1.0f;
}

__global__ __launch_bounds__(256) void sig_pde_raw(
    const float* __restrict__ X, const float* __restrict__ Y,
    float* __restrict__ outp)
{
    __shared__ float red[4];
    const int wv = threadIdx.x >> 6, lane = threadIdx.x & 63;
    const int B = blockIdx.x;
    int g, a, b;
    if (B < XY_BLOCKS) { g = 2; a = B >> 4; b = ((B & 15) << 2) + wv; }
    else {
        int t = B - XY_BLOCKS; g = 0;
        if (t >= TRI_BLOCKS) { t -= TRI_BLOCKS; g = 1; }
        int aa = 0;
        for (;;) { int nb = (67 - aa) >> 2; if (t < nb) break; t -= nb; ++aa; }
        a = aa; b = aa + (t << 2) + wv;
    }
    float weight = (g == 2) ? (-2.0f / 4096.0f)
                            : ((a == b ? 1.0f : 2.0f) / 4096.0f);
    if (g < 2 && b > 63) { b = 63; weight = 0.0f; }
    const float* P = (g == 1) ? Y : X;
    const float* Q = (g == 0) ? X : Y;
    f2 ya[8], yb[8];
    {
        const float* Qb = Q + b * 2048;
        const int j0 = lane << 1;
        const int j2 = (j0 + 2 <= 127) ? j0 + 2 : 127;
        const float4* A4 = (const float4*)(Qb + j0 * 16);
        const float4* B4 = (const float4*)(Qb + (j0 + 1) * 16);
        const float4* C4 = (const float4*)(Qb + j2 * 16);
#pragma unroll
        for (int q = 0; q < 4; ++q) {
            float4 ra = A4[q], rb = B4[q], rc = C4[q];
            ya[2*q]   = f2{rb.x - ra.x, rb.y - ra.y};
            ya[2*q+1] = f2{rb.z - ra.z, rb.w - ra.w};
            yb[2*q]   = f2{rc.x - rb.x, rc.y - rb.y};
            yb[2*q+1] = f2{rc.z - rb.z, rc.w - rb.w};
        }
    }
    const int dz = __builtin_amdgcn_mbcnt_lo(0u, 0u);
    const float4* Ar4 = (const float4*)(P + a * 2048) + dz;
    f2 xa[8], xb[8];
    float qpA, qpB;
    load_xrow(xa, Ar4, 0);
    {
        f2 s0 = 0.0f, s1 = 0.0f, t0 = 0.0f, t1 = 0.0f;
#pragma unroll
        for (int d = 0; d < 8; d += 2) {
            s0 = pk_fma(xa[d], ya[d], s0);   s1 = pk_fma(xa[d+1], ya[d+1], s1);
            t0 = pk_fma(xa[d], yb[d], t0);   t1 = pk_fma(xa[d+1], yb[d+1], t1);
        }
        const f2 sA = s0 + s1, sB = t0 + t1;
        qpA = (sA.x + sA.y) + 1.0f;
        qpB = (sB.x + sB.y) + 1.0f;
    }
    load_xrow(xa, Ar4, 1);
    float g_lo = 1.0f, g_hi = 1.0f;
    for (int r = 0; r < 126; r += 2) {
        load_xrow(xb, Ar4, r + 2);
        pde_row_q(xa, ya, yb, qpA, qpB, g_lo, g_hi, lane);
        load_xrow(xa, Ar4, r + 3);
        pde_row_q(xb, ya, yb, qpA, qpB, g_lo, g_hi, lane);
    }
    pde_row_q(xa, ya, yb, qpA, qpB, g_lo, g_hi, lane);
    const float kab = __builtin_bit_cast(float,
        __builtin_amdgcn_readlane(__builtin_bit_cast(int, g_lo), 63));
    if (lane == 0) red[wv] = weight * kab;
    __syncthreads();
    if (threadIdx.x == 0)
        atomicAdd(outp, (red[0] + red[1]) + (red[2] + red[3]));
}

extern "C" void kernel_launch(void* const* d_in, const int* in_sizes, int n_in,
                              void* d_out, int out_size, void* d_ws, size_t ws_size,
                              hipStream_t stream) {
    const float* X = (const float*)d_in[0];
    const float* Y = (const float*)d_in[1];
    float* out = (float*)d_out;
    float* ws  = (float*)d_ws;

    hipMemsetAsync(d_out, 0, sizeof(float), stream);   // capturable memset node
    if (ws_size >= (size_t)(2 * DINC_PER) * sizeof(float)) {
        sig_diff<<<254, 256, 0, stream>>>(X, Y, ws);
        sig_pde5<<<NBLOCKS, 256, 0, stream>>>(ws, out);
    } else {
        sig_pde_raw<<<NBLOCKS, 256, 0, stream>>>(X, Y, out);
    }
}

// Round 6
// 149.762 us; speedup vs baseline: 1.3420x; 1.3420x over previous
//
#include <hip/hip_runtime.h>

// Signature-kernel MMD via Goursat PDE — round 6.
// R5 postmortem: VMEM broadcast x-loads stalled the loop (VALUBusy 43%);
// x-row feed must stay on the scalar path (s_load, free vs VALU). R6 = R2's
// proven skeleton (diff precompute, 2112x4-wave grid, 1 pair/wave, DPP scan,
// SGPR x-rows) + (1) v_pk_fma_f32 with SGPR src0 — dots 32->16 instrs, zero
// v_movs; (2) explicit pipelining: row r+1's independent dots are emitted in
// the same region as row r's serial scan chain so the scheduler interleaves;
// s_load prefetch distance 2 rows.

typedef float f2 __attribute__((ext_vector_type(2)));

#define XY_BLOCKS 1024
#define TRI_BLOCKS 544
#define NBLOCKS (XY_BLOCKS + 2 * TRI_BLOCKS)   // 2112 blocks x 4 waves
#define DINC_PER 130048                         // 64*127*16 floats

template <int C, int RM, int BM, bool BC>
__device__ __forceinline__ float dpp0(float x) {
    return __builtin_bit_cast(float, __builtin_amdgcn_update_dpp(
        0, __builtin_bit_cast(int, x), C, RM, BM, BC));
}

// 64-lane inclusive prefix sum, pure VALU (6 dependent adds).
__device__ __forceinline__ float wave_scan_incl(float v) {
    v += dpp0<0x111, 0xf, 0xf, true>(v);   // row_shr:1
    v += dpp0<0x112, 0xf, 0xf, true>(v);   // row_shr:2
    v += dpp0<0x114, 0xf, 0xf, true>(v);   // row_shr:4
    v += dpp0<0x118, 0xf, 0xf, true>(v);   // row_shr:8
    v += dpp0<0x142, 0xa, 0xf, false>(v);  // row_bcast:15 -> rows 1,3
    v += dpp0<0x143, 0xc, 0xf, false>(v);  // row_bcast:31 -> rows 2,3
    return v;
}

// lane l gets lane l-1's x; lane 0 gets `oldv`.
__device__ __forceinline__ float wave_shr1(float x, float oldv) {
    return __builtin_bit_cast(float, __builtin_amdgcn_update_dpp(
        __builtin_bit_cast(int, oldv), __builtin_bit_cast(int, x),
        0x138, 0xf, 0xf, false));          // wave_shr:1
}

// packed dual-fp32 FMA, src0 from an SGPR pair (VOP3P: 1 sgpr read legal).
__device__ __forceinline__ f2 pk_fma_sv(f2 xs, f2 yv, f2 cv) {
    f2 d;
    asm("v_pk_fma_f32 %0, %1, %2, %3"
        : "=v"(d)
        : "s"(__builtin_bit_cast(long, xs)), "v"(yv), "v"(cv));
    return d;
}

// x row r via wave-uniform address -> s_load into SGPR pairs
__device__ __forceinline__ void load_xrow(f2* x, const float4* Ar, int r) {
#pragma unroll
    for (int q = 0; q < 4; ++q) {
        float4 v = Ar[4 * r + q];
        x[2*q]   = f2{v.x, v.y};
        x[2*q+1] = f2{v.z, v.w};
    }
}

// both per-lane dots for one row: i0 = inc(r,2l)-1, i1 = inc(r,2l+1)-1
__device__ __forceinline__ void row_dots(
    const f2* x, const f2* ya, const f2* yb, float& i0, float& i1)
{
    const f2 seed = f2{-0.25f, -0.25f};
    f2 a0 = seed, a1 = seed, b0 = seed, b1 = seed;
#pragma unroll
    for (int d = 0; d < 8; d += 2) {
        a0 = pk_fma_sv(x[d],   ya[d],   a0);
        a1 = pk_fma_sv(x[d+1], ya[d+1], a1);
        b0 = pk_fma_sv(x[d],   yb[d],   b0);
        b1 = pk_fma_sv(x[d+1], yb[d+1], b1);
    }
    const f2 sA = a0 + a1, sB = b0 + b1;
    i0 = sA.x + sA.y;
    i1 = sB.x + sB.y;
}

// serial part of one PDE row (neighbor fetch + scan + state update)
__device__ __forceinline__ void recur(
    float i0, float i1, float& g_lo, float& g_hi, int lane)
{
    const float gl = wave_shr1(g_hi, 1.0f);        // G[r][2l], lane0 -> 1
    const float c0 = fmaf(gl, i0, g_lo);
    const float c1 = (lane == 63) ? 0.0f : fmaf(g_lo, i1, g_hi);
    const float S = wave_scan_incl(c0 + c1);
    g_lo = (S - c1) + 1.0f;
    g_hi = S + 1.0f;
}

// ---- kernel 1: path increments X,Y -> ws ----
__global__ __launch_bounds__(256) void sig_diff(
    const float* __restrict__ X, const float* __restrict__ Y,
    float* __restrict__ dInc)
{
    int i = blockIdx.x * 256 + threadIdx.x;   // float4 id, 65024 total
    if (i >= 65024) return;
    int which = (i >= 32512) ? 1 : 0;
    int j = i - which * 32512;
    int a = j / 508;                          // 127*4 float4 per path
    int rq = j - a * 508;
    const float* S = which ? Y : X;
    const float4* p = (const float4*)(S + a * 2048) + rq;
    float4 v0 = p[0], v1 = p[4];
    float4 d;
    d.x = v1.x - v0.x; d.y = v1.y - v0.y;
    d.z = v1.z - v0.z; d.w = v1.w - v0.w;
    ((float4*)dInc)[i] = d;
}

// ---- kernel 2: PDE, 1 pair/wave, pipelined, fused block reduction ----
__global__ __launch_bounds__(256) void sig_pde6(
    const float* __restrict__ dInc, float* __restrict__ outp)
{
    __shared__ float red[4];
    const int wv = threadIdx.x >> 6, lane = threadIdx.x & 63;
    const int B = blockIdx.x;

    int g, a, b;
    if (B < XY_BLOCKS) {                       // XY gram: dense 64x64
        g = 2; a = B >> 4; b = ((B & 15) << 2) + wv;
    } else {                                   // XX / YY: upper triangle
        int t = B - XY_BLOCKS; g = 0;
        if (t >= TRI_BLOCKS) { t -= TRI_BLOCKS; g = 1; }
        int aa = 0;
        for (;;) { int nb = (67 - aa) >> 2; if (t < nb) break; t -= nb; ++aa; }
        a = aa; b = aa + (t << 2) + wv;
    }
    float weight = (g == 2) ? (-2.0f / 4096.0f)
                            : ((a == b ? 1.0f : 2.0f) / 4096.0f);
    if (g < 2 && b > 63) { b = 63; weight = 0.0f; }   // pad waves: masked

    const float* dA = (g == 1) ? (dInc + DINC_PER) : dInc;   // row paths
    const float* dB = (g == 0) ? dInc : (dInc + DINC_PER);   // col paths

    // per-lane dY cols j=2l, 2l+1 (VGPR pairs)
    f2 ya[8], yb[8];
    {
        const int j0 = lane << 1;
        const int j1 = (j0 + 1 < 127) ? j0 + 1 : 126;  // lane63 clamp (masked)
        const float4* A4 = (const float4*)(dB + b * 2032 + j0 * 16);
        const float4* B4 = (const float4*)(dB + b * 2032 + j1 * 16);
#pragma unroll
        for (int q = 0; q < 4; ++q) {
            float4 va = A4[q], vb = B4[q];
            ya[2*q]   = f2{va.x, va.y};  ya[2*q+1] = f2{va.z, va.w};
            yb[2*q]   = f2{vb.x, vb.y};  yb[2*q+1] = f2{vb.z, vb.w};
        }
    }

    // wave-uniform dX base -> s_load rows into SGPR pairs
    const int abase = __builtin_amdgcn_readfirstlane(a * 2032);
    const float4* Ar = (const float4*)(dA + abase);

    f2 xA[8], xB[8];
    load_xrow(xA, Ar, 0);
    load_xrow(xB, Ar, 1);

    float g_lo = 1.0f, g_hi = 1.0f;
    float i0c, i1c, i0n, i1n;
    row_dots(xA, ya, yb, i0c, i1c);            // row 0 incs

    // rows 0..125 in pairs; dots of row r+1 overlap recurrence of row r
    for (int r = 0; r < 126; r += 2) {
        load_xrow(xA, Ar, (r + 2 < 127) ? r + 2 : 126);   // prefetch
        row_dots(xB, ya, yb, i0n, i1n);        // row r+1 dots (independent)
        recur(i0c, i1c, g_lo, g_hi, lane);     // row r   scan (serial)
        load_xrow(xB, Ar, (r + 3 < 127) ? r + 3 : 126);   // prefetch
        row_dots(xA, ya, yb, i0c, i1c);        // row r+2 dots
        recur(i0n, i1n, g_lo, g_hi, lane);     // row r+1 scan
    }
    recur(i0c, i1c, g_lo, g_hi, lane);         // row 126

    const float kab = __builtin_bit_cast(float,
        __builtin_amdgcn_readlane(__builtin_bit_cast(int, g_lo), 63));
    if (lane == 0) red[wv] = weight * kab;
    __syncthreads();
    if (threadIdx.x == 0)
        atomicAdd(outp, (red[0] + red[1]) + (red[2] + red[3]));
}

// ---- fallback (ws too small): self-contained, raw inputs, q-trick ----
__global__ __launch_bounds__(256) void sig_pde_raw(
    const float* __restrict__ X, const float* __restrict__ Y,
    float* __restrict__ outp)
{
    __shared__ float red[4];
    const int wv = threadIdx.x >> 6, lane = threadIdx.x & 63;
    const int B = blockIdx.x;
    int g, a, b;
    if (B < XY_BLOCKS) { g = 2; a = B >> 4; b = ((B & 15) << 2) + wv; }
    else {
        int t = B - XY_BLOCKS; g = 0;
        if (t >= TRI_BLOCKS) { t -= TRI_BLOCKS; g = 1; }
        int aa = 0;
        for (;;) { int nb = (67 - aa) >> 2; if (t < nb) break; t -= nb; ++aa; }
        a = aa; b = aa + (t << 2) + wv;
    }
    float weight = (g == 2) ? (-2.0f / 4096.0f)
                            : ((a == b ? 1.0f : 2.0f) / 4096.0f);
    if (g < 2 && b > 63) { b = 63; weight = 0.0f; }
    const float* P = (g == 1) ? Y : X;
    const float* Q = (g == 0) ? X : Y;
    f2 ya[8], yb[8];
    {
        const float* Qb = Q + b * 2048;
        const int j0 = lane << 1;
        const int j2 = (j0 + 2 <= 127) ? j0 + 2 : 127;
        const float4* A4 = (const float4*)(Qb + j0 * 16);
        const float4* B4 = (const float4*)(Qb + (j0 + 1) * 16);
        const float4* C4 = (const float4*)(Qb + j2 * 16);
#pragma unroll
        for (int q = 0; q < 4; ++q) {
            float4 ra = A4[q], rb = B4[q], rc = C4[q];
            ya[2*q]   = f2{rb.x - ra.x, rb.y - ra.y};
            ya[2*q+1] = f2{rb.z - ra.z, rb.w - ra.w};
            yb[2*q]   = f2{rc.x - rb.x, rc.y - rb.y};
            yb[2*q+1] = f2{rc.z - rb.z, rc.w - rb.w};
        }
    }
    const int abase = __builtin_amdgcn_readfirstlane(a * 2048);
    const float4* Ar = (const float4*)(P + abase);
    f2 xA[8];
    float qpA = 1.0f, qpB = 1.0f, g_lo = 1.0f, g_hi = 1.0f;
    {
        load_xrow(xA, Ar, 0);
        float h0, h1;
        row_dots(xA, ya, yb, h0, h1);          // dot(x_0,y) - 1
        qpA = h0 + 1.0f; qpB = h1 + 1.0f;      // dot(x_0,y)
    }
    for (int r = 0; r < 127; ++r) {
        load_xrow(xA, Ar, r + 1);
        float h0, h1;
        row_dots(xA, ya, yb, h0, h1);          // dot(x_{r+1},y) - 1
        const float i0 = h0 - qpA;             // inc-1 = (h+1) - qp - 1... 
        const float i1 = h1 - qpB;             //  == h - (qp - 1) - 1 = h-qp
        qpA = h0 + 1.0f; qpB = h1 + 1.0f;
        recur(i0, i1, g_lo, g_hi, lane);
    }
    const float kab = __builtin_bit_cast(float,
        __builtin_amdgcn_readlane(__builtin_bit_cast(int, g_lo), 63));
    if (lane == 0) red[wv] = weight * kab;
    __syncthreads();
    if (threadIdx.x == 0)
        atomicAdd(outp, (red[0] + red[1]) + (red[2] + red[3]));
}

extern "C" void kernel_launch(void* const* d_in, const int* in_sizes, int n_in,
                              void* d_out, int out_size, void* d_ws, size_t ws_size,
                              hipStream_t stream) {
    const float* X = (const float*)d_in[0];
    const float* Y = (const float*)d_in[1];
    float* out = (float*)d_out;
    float* ws  = (float*)d_ws;

    hipMemsetAsync(d_out, 0, sizeof(float), stream);   // capturable memset node
    if (ws_size >= (size_t)(2 * DINC_PER) * sizeof(float)) {
        sig_diff<<<254, 256, 0, stream>>>(X, Y, ws);
        sig_pde6<<<NBLOCKS, 256, 0, stream>>>(ws, out);
    } else {
        sig_pde_raw<<<NBLOCKS, 256, 0, stream>>>(X, Y, out);
    }
}